// Round 1
// baseline (13508.388 us; speedup 1.0000x reference)
//
#include <hip/hip_runtime.h>

#define B_ROWS 4096
#define D_KEYS 50000
#define KDIM   64
#define NCOL   1000
#define SCALEF 300000.0f
#define EPSF   1e-4f

#define DC 64   // D-chunk
#define BT 64   // b-tile per block
#define NT 256  // n-tile per block (4 tiles cover 1024 >= 1000, masked)

// one wave per row of 64: out[r] = sum(a[r][:]^2)
__global__ void row_norm2_kernel(const float* __restrict__ a,
                                 float* __restrict__ out, int rows) {
    int wave = (blockIdx.x * blockDim.x + threadIdx.x) >> 6;
    int lane = threadIdx.x & 63;
    if (wave >= rows) return;
    float v = a[(size_t)wave * KDIM + lane];
    float s = v * v;
    #pragma unroll
    for (int off = 32; off > 0; off >>= 1) s += __shfl_down(s, off, 64);
    if (lane == 0) out[wave] = s;
}

__global__ __launch_bounds__(256, 1)
void varkeys_main_kernel(const float* __restrict__ x,
                         const float* __restrict__ keys,
                         const float* __restrict__ V,
                         const float* __restrict__ xn,
                         const float* __restrict__ kn,
                         float* __restrict__ out) {
    // pad 68 keeps float4 rows bank-uniform; ker stride 65 breaks d-major conflicts
    __shared__ float x_lds[BT][68];
    __shared__ float keys_lds[DC][68];
    __shared__ float ker_lds[DC][65];
    __shared__ float xn_lds[BT];
    __shared__ float kn_lds[DC];

    const int t = threadIdx.x;
    const int n0 = blockIdx.x * NT;   // 0,256,512,768
    const int b0 = blockIdx.y * BT;

    // ---- stage x tile + xn once (covered by first in-loop barrier) ----
    for (int q = t; q < BT * 16; q += 256) {
        int row = q >> 4, c4 = q & 15;
        float4 v = *(const float4*)(x + (size_t)(b0 + row) * KDIM + c4 * 4);
        *(float4*)&x_lds[row][c4 * 4] = v;
    }
    if (t < BT) xn_lds[t] = xn[b0 + t];

    // PV thread mapping: 64 n-threads (4 cols each) x 4 b-groups (16 rows each)
    const int tn = t & 63;
    const int tb = t >> 6;
    const int tb16 = tb * 16;
    const int n4 = n0 + 4 * tn;
    const bool nvalid = (n4 < NCOL);   // NCOL%4==0 so n4<NCOL implies n4+3<NCOL

    float4 acc[16];
    #pragma unroll
    for (int j = 0; j < 16; j++) acc[j] = make_float4(0.f, 0.f, 0.f, 0.f);

    // scores thread mapping: 16 d-threads x 16 b-threads, each 4d x 4b
    const int td = t & 15;
    const int tq = t >> 4;

    for (int d0 = 0; d0 < D_KEYS; d0 += DC) {
        const int dlim = min(DC, D_KEYS - d0);

        // ---- stage keys chunk + kn ----
        for (int q = t; q < DC * 16; q += 256) {
            int row = q >> 4, c4 = q & 15;
            if (d0 + row < D_KEYS) {
                float4 v = *(const float4*)(keys + (size_t)(d0 + row) * KDIM + c4 * 4);
                *(float4*)&keys_lds[row][c4 * 4] = v;
            }
        }
        if (t < DC) kn_lds[t] = (d0 + t < D_KEYS) ? kn[d0 + t] : 0.f;
        __syncthreads();

        // ---- scores: ker[d][b] = 1/((kn - 2*dot + xn)/SCALE + EPS) ----
        {
            float4 s[4][4];
            #pragma unroll
            for (int i = 0; i < 4; i++)
                #pragma unroll
                for (int j = 0; j < 4; j++) s[i][j] = make_float4(0.f, 0.f, 0.f, 0.f);
            #pragma unroll
            for (int k4 = 0; k4 < 16; k4++) {
                float4 kv[4], xv[4];
                #pragma unroll
                for (int i = 0; i < 4; i++) kv[i] = *(const float4*)&keys_lds[td + 16 * i][k4 * 4];
                #pragma unroll
                for (int j = 0; j < 4; j++) xv[j] = *(const float4*)&x_lds[tq + 16 * j][k4 * 4];
                #pragma unroll
                for (int i = 0; i < 4; i++)
                    #pragma unroll
                    for (int j = 0; j < 4; j++) {
                        s[i][j].x += kv[i].x * xv[j].x;
                        s[i][j].y += kv[i].y * xv[j].y;
                        s[i][j].z += kv[i].z * xv[j].z;
                        s[i][j].w += kv[i].w * xv[j].w;
                    }
            }
            #pragma unroll
            for (int i = 0; i < 4; i++)
                #pragma unroll
                for (int j = 0; j < 4; j++) {
                    int d = td + 16 * i, bb = tq + 16 * j;
                    float dot = s[i][j].x + s[i][j].y + s[i][j].z + s[i][j].w;
                    float dist = (kn_lds[d] - 2.0f * dot + xn_lds[bb]) * (1.0f / SCALEF) + EPSF;
                    ker_lds[d][bb] = 1.0f / dist;
                }
        }
        __syncthreads();

        // ---- PV: acc[b][n] += ker[d][b] * V[d][n] ----
        if (nvalid) {
            const float* vp = V + (size_t)d0 * NCOL + n4;
            for (int d = 0; d < dlim; d += 4) {
                float4 v0 = *(const float4*)(vp + (size_t)(d + 0) * NCOL);
                float4 v1 = *(const float4*)(vp + (size_t)(d + 1) * NCOL);
                float4 v2 = *(const float4*)(vp + (size_t)(d + 2) * NCOL);
                float4 v3 = *(const float4*)(vp + (size_t)(d + 3) * NCOL);
                #pragma unroll
                for (int j = 0; j < 16; j++) {
                    float k0 = ker_lds[d + 0][tb16 + j];
                    float k1 = ker_lds[d + 1][tb16 + j];
                    float k2 = ker_lds[d + 2][tb16 + j];
                    float k3 = ker_lds[d + 3][tb16 + j];
                    acc[j].x += k0 * v0.x + k1 * v1.x + k2 * v2.x + k3 * v3.x;
                    acc[j].y += k0 * v0.y + k1 * v1.y + k2 * v2.y + k3 * v3.y;
                    acc[j].z += k0 * v0.z + k1 * v1.z + k2 * v2.z + k3 * v3.z;
                    acc[j].w += k0 * v0.w + k1 * v1.w + k2 * v2.w + k3 * v3.w;
                }
            }
        }
        // top-of-loop barrier (after next keys stage) protects ker_lds rewrite
    }

    if (nvalid) {
        #pragma unroll
        for (int j = 0; j < 16; j++) {
            int b = b0 + tb16 + j;
            *(float4*)(out + (size_t)b * NCOL + n4) = acc[j];
        }
    }
}

__global__ void normalize_kernel(float* __restrict__ out) {
    const int b = blockIdx.x;
    float* row = out + (size_t)b * NCOL;
    const int t = threadIdx.x;
    float s = 0.f;
    for (int n = t; n < NCOL; n += 256) s += row[n];
    __shared__ float red[4];
    #pragma unroll
    for (int off = 32; off > 0; off >>= 1) s += __shfl_down(s, off, 64);
    if ((t & 63) == 0) red[t >> 6] = s;
    __syncthreads();
    float inv = 1.0f / (red[0] + red[1] + red[2] + red[3]);
    for (int n = t; n < NCOL; n += 256) row[n] *= inv;
}

extern "C" void kernel_launch(void* const* d_in, const int* in_sizes, int n_in,
                              void* d_out, int out_size, void* d_ws, size_t ws_size,
                              hipStream_t stream) {
    const float* x    = (const float*)d_in[0];
    const float* keys = (const float*)d_in[1];
    const float* V    = (const float*)d_in[2];
    float* out = (float*)d_out;
    float* xn = (float*)d_ws;            // 4096 floats
    float* kn = xn + B_ROWS;             // 50000 floats

    row_norm2_kernel<<<B_ROWS / 4, 256, 0, stream>>>(x, xn, B_ROWS);
    row_norm2_kernel<<<D_KEYS / 4, 256, 0, stream>>>(keys, kn, D_KEYS);

    dim3 grid(4, BT == 64 ? B_ROWS / BT : 0);  // (n-tiles, b-tiles) = (4, 64)
    varkeys_main_kernel<<<grid, 256, 0, stream>>>(x, keys, V, xn, kn, out);

    normalize_kernel<<<B_ROWS, 256, 0, stream>>>(out);
}

// Round 2
// 1369.296 us; speedup vs baseline: 9.8652x; 9.8652x over previous
//
#include <hip/hip_runtime.h>

typedef __attribute__((ext_vector_type(8))) short short8;
typedef __attribute__((ext_vector_type(16))) float f32x16;
typedef unsigned short u16;
typedef unsigned int u32;

#define B_ROWS 4096
#define D_KEYS 50000
#define DPAD   50048
#define KDIM   64
#define NCOL   1000
#define NPAD   1024
#define SCALEF 300000.0f
#define EPSF   1e-4f
#define NCHUNK_HALF 391   // 782/2 chunks of 64 per D-split
#define D_HALF 25024      // 391*64

// ---------------- helpers ----------------

__device__ __forceinline__ u16 f2bf(float f) {          // RNE float->bf16
    u32 u = __builtin_bit_cast(u32, f);
    u = (u + 0x7FFFu + ((u >> 16) & 1u)) >> 16;
    return (u16)u;
}

__device__ __forceinline__ void glds16(const void* g, void* l) {
    __builtin_amdgcn_global_load_lds(
        (const __attribute__((address_space(1))) u32*)(uintptr_t)g,
        (__attribute__((address_space(3))) u32*)(uintptr_t)l, 16, 0, 0);
}

// ---------------- pre-pass kernels ----------------

__global__ void prep_x_kernel(const float* __restrict__ x,
                              u16* __restrict__ x_bf, float* __restrict__ xn) {
    int row = (blockIdx.x * blockDim.x + threadIdx.x) >> 6;
    int lane = threadIdx.x & 63;
    if (row >= B_ROWS) return;
    float v = x[(size_t)row * KDIM + lane];
    x_bf[(size_t)row * KDIM + lane] = f2bf(v);
    float s = v * v;
    #pragma unroll
    for (int off = 32; off > 0; off >>= 1) s += __shfl_down(s, off, 64);
    if (lane == 0) xn[row] = s;
}

__global__ void prep_keys_kernel(const float* __restrict__ keys,
                                 u16* __restrict__ keys_bf, float* __restrict__ kn) {
    int row = (blockIdx.x * blockDim.x + threadIdx.x) >> 6;
    int lane = threadIdx.x & 63;
    if (row >= DPAD) return;
    float v = (row < D_KEYS) ? keys[(size_t)row * KDIM + lane] : 0.f;
    keys_bf[(size_t)row * KDIM + lane] = f2bf(v);
    float s = v * v;
    #pragma unroll
    for (int off = 32; off > 0; off >>= 1) s += __shfl_down(s, off, 64);
    if (lane == 0) kn[row] = s;
}

// V (50000x1000 f32, row-major) -> Vt (1024x50048 bf16, d contiguous), zero-padded
__global__ void prep_v_kernel(const float* __restrict__ V, u16* __restrict__ vt) {
    __shared__ float tile[64][65];
    const int d0 = blockIdx.x * 64;
    const int n0 = blockIdx.y * 64;
    const int t = threadIdx.x;
    #pragma unroll
    for (int p = 0; p < 16; p++) {
        int idx = p * 256 + t;
        int di = idx >> 6, nj = idx & 63;
        int d = d0 + di, n = n0 + nj;
        float v = (d < D_KEYS && n < NCOL) ? V[(size_t)d * NCOL + n] : 0.f;
        tile[di][nj] = v;
    }
    __syncthreads();
    #pragma unroll
    for (int p = 0; p < 16; p++) {
        int idx = p * 256 + t;
        int ni = idx >> 6, dj = idx & 63;
        vt[(size_t)(n0 + ni) * DPAD + d0 + dj] = f2bf(tile[dj][ni]);
    }
}

// ---------------- main MFMA kernel ----------------
// grid (8 n-tiles, 32 b-tiles, 2 d-splits), 256 threads (4 waves)
// per chunk: scores ker(64d x 128b) via mfma 32x32x16 (m=d, n=b), then
// PV acc(128b x 128n) += ker^T(b,d) x Vt(d,n). XOR-swizzled LDS chunks.
__global__ __launch_bounds__(256, 2)
void varkeys_mfma_kernel(const u16* __restrict__ x_bf,
                         const u16* __restrict__ keys_bf,
                         const u16* __restrict__ vt_bf,
                         const float* __restrict__ xn,
                         const float* __restrict__ kn,
                         float* __restrict__ partial) {
    __shared__ u16 keys_lds[64 * 64];
    __shared__ u16 v_lds[128 * 64];
    __shared__ u16 ker_lds[128 * 64];
    __shared__ float kn_lds[64];

    const int t = threadIdx.x;
    const int w = t >> 6;
    const int lane = t & 63;
    const int half = lane >> 5;
    const int l31 = lane & 31;

    const int n0 = blockIdx.x * 128;
    const int b0 = blockIdx.y * 128;
    const int dz = blockIdx.z;
    const int dbase = dz * D_HALF;

    const int bl = 32 * w + l31;        // this lane's b row (scores col / PV A row)
    const int bg = b0 + bl;
    const float xn_v = xn[bg];

    // x fragments (scores B operand) held permanently in VGPRs
    short8 xfrag[4];
    #pragma unroll
    for (int kk = 0; kk < 4; kk++)
        xfrag[kk] = *(const short8*)(x_bf + (size_t)bg * KDIM + kk * 16 + half * 8);

    f32x16 acc[4];
    #pragma unroll
    for (int nt = 0; nt < 4; nt++)
        #pragma unroll
        for (int i = 0; i < 16; i++) acc[nt][i] = 0.f;

    const int srow = lane >> 3;                 // 0..7
    const int cg = (lane & 7) ^ srow;           // swizzled global chunk

    for (int c = 0; c < NCHUNK_HALF; c++) {
        const int d0 = dbase + c * 64;

        // ---- stage keys (8KB) + Vt (16KB) chunk, swizzled ----
        #pragma unroll
        for (int q = 0; q < 2; q++) {
            int r = 8 * (w * 2 + q) + srow;
            glds16(keys_bf + (size_t)(d0 + r) * KDIM + cg * 8,
                   &keys_lds[(w * 2 + q) * 512]);
        }
        #pragma unroll
        for (int q = 0; q < 4; q++) {
            int r = 8 * (w * 4 + q) + srow;
            glds16(vt_bf + (size_t)(n0 + r) * DPAD + d0 + cg * 8,
                   &v_lds[(w * 4 + q) * 512]);
        }
        if (t < 64) kn_lds[t] = kn[d0 + t];
        __syncthreads();

        // ---- scores: each wave computes ker rows for its own b-strip ----
        #pragma unroll
        for (int mt = 0; mt < 2; mt++) {
            f32x16 s;
            #pragma unroll
            for (int i = 0; i < 16; i++) s[i] = 0.f;
            const int dl = mt * 32 + l31;
            #pragma unroll
            for (int kk = 0; kk < 4; kk++) {
                int cidx = kk * 2 + half;
                short8 af = *(const short8*)&keys_lds[dl * 64 + ((cidx ^ (dl & 7)) * 8)];
                s = __builtin_amdgcn_mfma_f32_32x32x16_bf16(af, xfrag[kk], s, 0, 0, 0);
            }
            // epilogue: dist -> rcp -> bf16 pair-packed writes to ker_lds[b][d]
            #pragma unroll
            for (int rp = 0; rp < 8; rp++) {
                int r0 = 2 * rp;
                int dloc = mt * 32 + (r0 & 3) + 8 * (r0 >> 2) + 4 * half;
                float dist0 = (kn_lds[dloc] + xn_v - 2.f * s[r0]) * (1.f / SCALEF) + EPSF;
                float dist1 = (kn_lds[dloc + 1] + xn_v - 2.f * s[r0 + 1]) * (1.f / SCALEF) + EPSF;
                float k0 = __builtin_amdgcn_rcpf(dist0);
                float k1 = __builtin_amdgcn_rcpf(dist1);
                if (d0 + dloc >= D_KEYS) k0 = 0.f;
                if (d0 + dloc + 1 >= D_KEYS) k1 = 0.f;
                u32 pk = (u32)f2bf(k0) | ((u32)f2bf(k1) << 16);
                int c2 = dloc >> 3;
                int addr = bl * 64 + ((c2 ^ (bl & 7)) * 8) + (dloc & 7);
                *(u32*)&ker_lds[addr] = pk;
            }
        }

        // ---- PV: acc += ker(A, m=b) x Vt(B, n=col) ---- (same-wave ker reuse, no barrier)
        #pragma unroll
        for (int kk = 0; kk < 4; kk++) {
            int cidx = kk * 2 + half;
            short8 kf = *(const short8*)&ker_lds[bl * 64 + ((cidx ^ (bl & 7)) * 8)];
            #pragma unroll
            for (int nt = 0; nt < 4; nt++) {
                int nl = nt * 32 + l31;
                short8 vf = *(const short8*)&v_lds[nl * 64 + ((cidx ^ (nl & 7)) * 8)];
                acc[nt] = __builtin_amdgcn_mfma_f32_32x32x16_bf16(kf, vf, acc[nt], 0, 0, 0);
            }
        }
        __syncthreads();    // protect keys_lds/v_lds before next stage
    }

    // ---- store partial (C layout: col=lane&31 -> n, row -> b) ----
    float* pout = partial + (size_t)dz * B_ROWS * NCOL;
    #pragma unroll
    for (int nt = 0; nt < 4; nt++) {
        int n = n0 + nt * 32 + l31;
        if (n < NCOL) {
            #pragma unroll
            for (int r = 0; r < 16; r++) {
                int brow = b0 + 32 * w + (r & 3) + 8 * (r >> 2) + 4 * half;
                pout[(size_t)brow * NCOL + n] = acc[nt][r];
            }
        }
    }
}

// sum the two D-split partials, row-normalize
__global__ void finish_kernel(const float* __restrict__ partial, float* __restrict__ out) {
    const int b = blockIdx.x;
    const int t = threadIdx.x;
    const float* p0 = partial + (size_t)b * NCOL;
    const float* p1 = partial + (size_t)B_ROWS * NCOL + (size_t)b * NCOL;
    float s = 0.f;
    for (int n = t; n < NCOL; n += 256) s += p0[n] + p1[n];
    __shared__ float red[4];
    #pragma unroll
    for (int off = 32; off > 0; off >>= 1) s += __shfl_down(s, off, 64);
    if ((t & 63) == 0) red[t >> 6] = s;
    __syncthreads();
    float inv = 1.0f / (red[0] + red[1] + red[2] + red[3]);
    for (int n = t; n < NCOL; n += 256) out[(size_t)b * NCOL + n] = (p0[n] + p1[n]) * inv;
}

// ================= fallback fp32 path (round-1, known-correct) =================

__global__ void row_norm2_kernel(const float* __restrict__ a,
                                 float* __restrict__ out, int rows) {
    int wave = (blockIdx.x * blockDim.x + threadIdx.x) >> 6;
    int lane = threadIdx.x & 63;
    if (wave >= rows) return;
    float v = a[(size_t)wave * KDIM + lane];
    float s = v * v;
    #pragma unroll
    for (int off = 32; off > 0; off >>= 1) s += __shfl_down(s, off, 64);
    if (lane == 0) out[wave] = s;
}

#define DC 64
#define BT 64
#define NT 256

__global__ __launch_bounds__(256, 1)
void varkeys_main_kernel(const float* __restrict__ x,
                         const float* __restrict__ keys,
                         const float* __restrict__ V,
                         const float* __restrict__ xn,
                         const float* __restrict__ kn,
                         float* __restrict__ out) {
    __shared__ float x_lds[BT][68];
    __shared__ float keys_lds[DC][68];
    __shared__ float ker_lds[DC][65];
    __shared__ float xn_lds[BT];
    __shared__ float kn_lds[DC];
    const int t = threadIdx.x;
    const int n0 = blockIdx.x * NT;
    const int b0 = blockIdx.y * BT;
    for (int q = t; q < BT * 16; q += 256) {
        int row = q >> 4, c4 = q & 15;
        float4 v = *(const float4*)(x + (size_t)(b0 + row) * KDIM + c4 * 4);
        *(float4*)&x_lds[row][c4 * 4] = v;
    }
    if (t < BT) xn_lds[t] = xn[b0 + t];
    const int tn = t & 63;
    const int tb = t >> 6;
    const int tb16 = tb * 16;
    const int n4 = n0 + 4 * tn;
    const bool nvalid = (n4 < NCOL);
    float4 acc[16];
    #pragma unroll
    for (int j = 0; j < 16; j++) acc[j] = make_float4(0.f, 0.f, 0.f, 0.f);
    const int td = t & 15;
    const int tq = t >> 4;
    for (int d0 = 0; d0 < D_KEYS; d0 += DC) {
        const int dlim = min(DC, D_KEYS - d0);
        for (int q = t; q < DC * 16; q += 256) {
            int row = q >> 4, c4 = q & 15;
            if (d0 + row < D_KEYS) {
                float4 v = *(const float4*)(keys + (size_t)(d0 + row) * KDIM + c4 * 4);
                *(float4*)&keys_lds[row][c4 * 4] = v;
            }
        }
        if (t < DC) kn_lds[t] = (d0 + t < D_KEYS) ? kn[d0 + t] : 0.f;
        __syncthreads();
        {
            float4 s[4][4];
            #pragma unroll
            for (int i = 0; i < 4; i++)
                #pragma unroll
                for (int j = 0; j < 4; j++) s[i][j] = make_float4(0.f, 0.f, 0.f, 0.f);
            #pragma unroll
            for (int k4 = 0; k4 < 16; k4++) {
                float4 kv[4], xv[4];
                #pragma unroll
                for (int i = 0; i < 4; i++) kv[i] = *(const float4*)&keys_lds[td + 16 * i][k4 * 4];
                #pragma unroll
                for (int j = 0; j < 4; j++) xv[j] = *(const float4*)&x_lds[tq + 16 * j][k4 * 4];
                #pragma unroll
                for (int i = 0; i < 4; i++)
                    #pragma unroll
                    for (int j = 0; j < 4; j++) {
                        s[i][j].x += kv[i].x * xv[j].x;
                        s[i][j].y += kv[i].y * xv[j].y;
                        s[i][j].z += kv[i].z * xv[j].z;
                        s[i][j].w += kv[i].w * xv[j].w;
                    }
            }
            #pragma unroll
            for (int i = 0; i < 4; i++)
                #pragma unroll
                for (int j = 0; j < 4; j++) {
                    int d = td + 16 * i, bb = tq + 16 * j;
                    float dot = s[i][j].x + s[i][j].y + s[i][j].z + s[i][j].w;
                    float dist = (kn_lds[d] - 2.0f * dot + xn_lds[bb]) * (1.0f / SCALEF) + EPSF;
                    ker_lds[d][bb] = 1.0f / dist;
                }
        }
        __syncthreads();
        if (nvalid) {
            const float* vp = V + (size_t)d0 * NCOL + n4;
            for (int d = 0; d < dlim; d += 4) {
                float4 v0 = *(const float4*)(vp + (size_t)(d + 0) * NCOL);
                float4 v1 = *(const float4*)(vp + (size_t)(d + 1) * NCOL);
                float4 v2 = *(const float4*)(vp + (size_t)(d + 2) * NCOL);
                float4 v3 = *(const float4*)(vp + (size_t)(d + 3) * NCOL);
                #pragma unroll
                for (int j = 0; j < 16; j++) {
                    float k0 = ker_lds[d + 0][tb16 + j];
                    float k1 = ker_lds[d + 1][tb16 + j];
                    float k2 = ker_lds[d + 2][tb16 + j];
                    float k3 = ker_lds[d + 3][tb16 + j];
                    acc[j].x += k0 * v0.x + k1 * v1.x + k2 * v2.x + k3 * v3.x;
                    acc[j].y += k0 * v0.y + k1 * v1.y + k2 * v2.y + k3 * v3.y;
                    acc[j].z += k0 * v0.z + k1 * v1.z + k2 * v2.z + k3 * v3.z;
                    acc[j].w += k0 * v0.w + k1 * v1.w + k2 * v2.w + k3 * v3.w;
                }
            }
        }
    }
    if (nvalid) {
        #pragma unroll
        for (int j = 0; j < 16; j++) {
            int b = b0 + tb16 + j;
            *(float4*)(out + (size_t)b * NCOL + n4) = acc[j];
        }
    }
}

__global__ void normalize_kernel(float* __restrict__ out) {
    const int b = blockIdx.x;
    float* row = out + (size_t)b * NCOL;
    const int t = threadIdx.x;
    float s = 0.f;
    for (int n = t; n < NCOL; n += 256) s += row[n];
    __shared__ float red[4];
    #pragma unroll
    for (int off = 32; off > 0; off >>= 1) s += __shfl_down(s, off, 64);
    if ((t & 63) == 0) red[t >> 6] = s;
    __syncthreads();
    float inv = 1.0f / (red[0] + red[1] + red[2] + red[3]);
    for (int n = t; n < NCOL; n += 256) row[n] *= inv;
}

// ================= launch =================

extern "C" void kernel_launch(void* const* d_in, const int* in_sizes, int n_in,
                              void* d_out, int out_size, void* d_ws, size_t ws_size,
                              hipStream_t stream) {
    const float* x    = (const float*)d_in[0];
    const float* keys = (const float*)d_in[1];
    const float* V    = (const float*)d_in[2];
    float* out = (float*)d_out;

    // ws layout (256B-aligned offsets)
    const size_t off_xn  = 0;                         // 4096 f32
    const size_t off_kn  = 16384;                     // 50048 f32
    const size_t off_xbf = 216576;                    // 4096x64 bf16
    const size_t off_kbf = 740864;                    // 50048x64 bf16
    const size_t off_vt  = 7147008;                   // 1024x50048 bf16
    const size_t off_p   = 109645312;                 // 2 x 4096x1000 f32
    const size_t total   = 142413312;

    if (ws_size >= total) {
        char* ws = (char*)d_ws;
        float* xn = (float*)(ws + off_xn);
        float* kn = (float*)(ws + off_kn);
        u16* x_bf = (u16*)(ws + off_xbf);
        u16* k_bf = (u16*)(ws + off_kbf);
        u16* vt   = (u16*)(ws + off_vt);
        float* partial = (float*)(ws + off_p);

        prep_x_kernel<<<B_ROWS / 4, 256, 0, stream>>>(x, x_bf, xn);
        prep_keys_kernel<<<DPAD / 4, 256, 0, stream>>>(keys, k_bf, kn);
        prep_v_kernel<<<dim3(DPAD / 64, NPAD / 64), 256, 0, stream>>>(V, vt);
        varkeys_mfma_kernel<<<dim3(8, 32, 2), 256, 0, stream>>>(x_bf, k_bf, vt, xn, kn, partial);
        finish_kernel<<<B_ROWS, 256, 0, stream>>>(partial, out);
    } else {
        float* xn = (float*)d_ws;
        float* kn = xn + B_ROWS;
        row_norm2_kernel<<<B_ROWS / 4, 256, 0, stream>>>(x, xn, B_ROWS);
        row_norm2_kernel<<<D_KEYS / 4 + 1, 256, 0, stream>>>(keys, kn, D_KEYS);
        dim3 grid(4, B_ROWS / BT);
        varkeys_main_kernel<<<grid, 256, 0, stream>>>(x, keys, V, xn, kn, out);
        normalize_kernel<<<B_ROWS, 256, 0, stream>>>(out);
    }
}